// Round 14
// baseline (2841.934 us; speedup 1.0000x reference)
//
#include <hip/hip_runtime.h>
#include <hip/hip_bf16.h>
#include <hip/hip_fp16.h>

#define NN 50000
#define NE 800000
#define NP 50176          // 196*256 padded node count for scan
#define NBLK 196

#define E8(M)  M(0) M(1) M(2) M(3) M(4) M(5) M(6) M(7)
#define E8B(M) M(8) M(9) M(10) M(11) M(12) M(13) M(14) M(15)
#define E16(M) E8(M) E8B(M)

typedef __attribute__((ext_vector_type(8))) _Float16 hfrag;  // 8 f16 (4 VGPR)
typedef __attribute__((ext_vector_type(4))) float facc;      // 4 fp32 acc

__device__ __forceinline__ float us2f_bf16(unsigned short u){
    unsigned v = ((unsigned)u) << 16; float f; __builtin_memcpy(&f, &v, 4); return f;
}
__device__ __forceinline__ float us2f_f16(unsigned short u){
    __half h; __builtin_memcpy(&h, &u, 2); return __half2float(h);
}
// mode: 0=bf16, 1=f16, 2=fp32
__device__ __forceinline__ float ldf3(const void* p, size_t i, int mode){
    if (mode == 2) return ((const float*)p)[i];
    unsigned short u = ((const unsigned short*)p)[i];
    return (mode == 0) ? us2f_bf16(u) : us2f_f16(u);
}
__device__ __forceinline__ int ldi(const int* p, size_t j, int i64){
    return i64 ? p[2*j] : p[j];
}
// broadcast lane l's value via v_readlane (VALU pipe -> SGPR, no LDS)
__device__ __forceinline__ float rl(float v, int l){
    return __uint_as_float(__builtin_amdgcn_readlane(__float_as_uint(v), l));
}

// ---------------- sentinel fill (fp32 output) ----------------
__global__ void fill_k(float* __restrict__ out, int n, float cval){
    int i = blockIdx.x*256 + threadIdx.x;
    if (i < n) out[i] = cval;
}

// ---------------- probes (validated) ----------------
__global__ void probe_f_k(const unsigned short* __restrict__ hf, int* __restrict__ flags){
    __shared__ int cnt;
    if (threadIdx.x == 0) cnt = 0;
    __syncthreads();
    int c = 0;
    for (int idx = threadIdx.x; idx < 2048; idx += 256){
        int ex = (hf[2*idx] >> 7) & 0xFF;
        if (ex >= 118 && ex <= 131) c++;
    }
    atomicAdd(&cnt, c);
    __syncthreads();
    if (threadIdx.x == 0){
        int inb = cnt;
        int mode;
        if (inb >= 1536)      mode = 0;     // bf16
        else if (inb <= 205)  mode = 2;     // fp32
        else                  mode = 1;     // f16
        flags[0] = mode;
    }
}
__global__ void probe_i_k(const int* __restrict__ d, int* __restrict__ flags){
    __shared__ int nz;
    if (threadIdx.x == 0) nz = 0;
    __syncthreads();
    int c = 0;
    for (int idx = threadIdx.x; idx < 2048; idx += 256){
        if (d[2*idx + 1] != 0) c++;
    }
    atomicAdd(&nz, c);
    __syncthreads();
    if (threadIdx.x == 0) flags[1] = (nz < 100) ? 1 : 0;
}

// ---------------- weight conversion ----------------
__global__ void cvt_k(const void* __restrict__ src, float* __restrict__ dst, int n,
                      const int* __restrict__ flags){
    int m = flags[0];
    int i = blockIdx.x*256 + threadIdx.x;
    if (i < n) dst[i] = ldf3(src, i, m);
}

// ---------------- pack per-layer WC into MFMA B-fragment layout (f16) ------
// For 16x16x32 (f16, same layout as validated bf16): lane holds B[k][col],
// k = s*32 + (lane>>4)*8 + j, col = ct*16 + (lane&15).
// WBf[l*4096 + (ct*2+s)*512 + lane*8 + j]
__global__ void packb_k(const float* __restrict__ Wlc, unsigned short* __restrict__ WBf){
    int i = blockIdx.x*256 + threadIdx.x;     // 0..16383
    int l = i >> 12, r = i & 4095;
    int ct2s = r >> 9, lane = (r >> 3) & 63, j = r & 7;
    int ct = ct2s >> 1, s = ct2s & 1;
    int k  = s*32 + (lane >> 4)*8 + j;
    int col = ct*16 + (lane & 15);
    const float* WC = Wlc + (size_t)l*5*4096 + 4*4096;
    _Float16 hv = (_Float16)WC[k*64 + col];   // RNE
    unsigned short u; __builtin_memcpy(&u, &hv, 2);
    WBf[i] = u;
}

// ---------------- node embedding: wave per node (validated) ----------------
__global__ __launch_bounds__(256) void embed_k(const void* __restrict__ hf,
        const float* __restrict__ W, const float* __restrict__ b,
        float* __restrict__ h, const int* __restrict__ flags){
    int f = flags[0];
    int t = threadIdx.x, c = t & 63;
    int i = blockIdx.x*4 + (t >> 6);
    float a = b[c];
    #pragma unroll
    for (int k=0;k<6;k++) a += ldf3(hf, (size_t)i*6+k, f) * W[k*64+c];
    h[(size_t)i*64+c] = a;
}

// ---------------- CSR build (counting sort by dst, validated) ----------------
__global__ void zero_cnt_k(int* __restrict__ cnt){
    int i = blockIdx.x*256 + threadIdx.x;
    cnt[i] = 0;
}
__global__ void hist_k(const int* __restrict__ dst, int* __restrict__ cnt,
                       const int* __restrict__ flags){
    int i64 = flags[1];
    int j = blockIdx.x*256 + threadIdx.x;
    atomicAdd(&cnt[ldi(dst, j, i64)], 1);
}
__global__ void scan1_k(const int* __restrict__ cnt, int* __restrict__ row_start,
                        int* __restrict__ bsum){
    __shared__ int s[256];
    int t = threadIdx.x;
    int i = blockIdx.x*256 + t;
    int v = cnt[i];
    s[t] = v; __syncthreads();
    #pragma unroll
    for (int off=1; off<256; off<<=1){
        int add = (t>=off) ? s[t-off] : 0;
        __syncthreads();
        s[t] += add;
        __syncthreads();
    }
    row_start[i] = s[t] - v;
    if (t==255) bsum[blockIdx.x] = s[255];
}
__global__ void scan2_k(const int* __restrict__ bsum, int* __restrict__ boff){
    __shared__ int s[256];
    int t = threadIdx.x;
    int v = (t < NBLK) ? bsum[t] : 0;
    s[t] = v; __syncthreads();
    #pragma unroll
    for (int off=1; off<256; off<<=1){
        int add = (t>=off) ? s[t-off] : 0;
        __syncthreads();
        s[t] += add;
        __syncthreads();
    }
    if (t < NBLK) boff[t] = s[t] - v;
}
__global__ void scan3_k(int* __restrict__ row_start, const int* __restrict__ boff,
                        int* __restrict__ cursor){
    int i = blockIdx.x*256 + threadIdx.x;
    int x = row_start[i] + boff[blockIdx.x];
    row_start[i] = x;
    cursor[i] = x;
}
__global__ void scatter_k(const int* __restrict__ dst, int* __restrict__ cursor,
                          int* __restrict__ perm, const int* __restrict__ flags){
    int i64 = flags[1];
    int j = blockIdx.x*256 + threadIdx.x;
    int d = ldi(dst, j, i64);
    int p = atomicAdd(&cursor[d], 1);
    perm[p] = j;
}

// ---------------- e init (f16, CSR order) + fused meta build ----------------
// meta[p] = src16 | ((dst&7) << 16), written into perm's own storage.
__global__ void einit_k(const void* __restrict__ ef, const float* __restrict__ Wee,
                        const float* __restrict__ bee, const int* perm,
                        int* meta, const int* __restrict__ src,
                        const int* __restrict__ dst,
                        _Float16* __restrict__ e, const int* __restrict__ flags){
    int f = flags[0], i64 = flags[1];
    int tid = blockIdx.x*256 + threadIdx.x;
    int c = tid & 63, p = tid >> 6;
    int j = perm[p];
    float f0 = ldf3(ef, (size_t)j*2+0, f), f1 = ldf3(ef, (size_t)j*2+1, f);
    e[(size_t)p*64+c] = (_Float16)(bee[c] + f0*Wee[c] + f1*Wee[64+c]);
    if (c == 0)
        meta[p] = (ldi(src, j, i64) & 0xffff) | ((ldi(dst, j, i64) & 7) << 16);
    if (p < 16 && c == 1) meta[NE + p] = 0;
}

// ---------------- per-layer node transforms: 4 nodes per WAVE (f16 out) ----
// EB16[i][0:64)=Eh, [64:128)=Bh;  AD16[i][0:64)=Ah, [64:128)=Dh+bC.
// Weight read once per wave, reused for 4 nodes (validated R13 structure).
__global__ __launch_bounds__(256) void node4_k(int l, const float* __restrict__ h,
        const float* __restrict__ Wlc, const float* __restrict__ blc,
        _Float16* __restrict__ EB, _Float16* __restrict__ AD){
    int t = threadIdx.x, c = t & 63, w = t >> 6;
    int i0 = blockIdx.x*16 + w*4;
    const float* WA = Wlc + (size_t)l*5*4096;
    const float* WB = WA + 4096;
    const float* WD = WA + 2*4096;
    const float* WE = WA + 3*4096;
    const float* bm = blc + (size_t)l*320;
    float hv0 = h[(size_t)(i0+0)*64 + c];
    float hv1 = h[(size_t)(i0+1)*64 + c];
    float hv2 = h[(size_t)(i0+2)*64 + c];
    float hv3 = h[(size_t)(i0+3)*64 + c];
    float ba = bm[c], bb = bm[64+c], bd = bm[128+c], be = bm[192+c];
    float ao0=ba, ao1=ba, ao2=ba, ao3=ba;
    float bo0=bb, bo1=bb, bo2=bb, bo3=bb;
    float do0=bd, do1=bd, do2=bd, do3=bd;
    float eo0=be, eo1=be, eo2=be, eo3=be;
    #pragma unroll 8
    for (int k=0;k<64;k++){
        float wa = WA[k*64+c], wb = WB[k*64+c], wd = WD[k*64+c], we = WE[k*64+c];
        float h0 = rl(hv0,k), h1 = rl(hv1,k), h2 = rl(hv2,k), h3 = rl(hv3,k);
        ao0 = fmaf(h0, wa, ao0); ao1 = fmaf(h1, wa, ao1);
        ao2 = fmaf(h2, wa, ao2); ao3 = fmaf(h3, wa, ao3);
        bo0 = fmaf(h0, wb, bo0); bo1 = fmaf(h1, wb, bo1);
        bo2 = fmaf(h2, wb, bo2); bo3 = fmaf(h3, wb, bo3);
        do0 = fmaf(h0, wd, do0); do1 = fmaf(h1, wd, do1);
        do2 = fmaf(h2, wd, do2); do3 = fmaf(h3, wd, do3);
        eo0 = fmaf(h0, we, eo0); eo1 = fmaf(h1, we, eo1);
        eo2 = fmaf(h2, we, eo2); eo3 = fmaf(h3, we, eo3);
    }
    float bc = bm[256+c];
    EB[(size_t)(i0+0)*128 + c] = (_Float16)eo0;
    EB[(size_t)(i0+0)*128 + 64 + c] = (_Float16)bo0;
    EB[(size_t)(i0+1)*128 + c] = (_Float16)eo1;
    EB[(size_t)(i0+1)*128 + 64 + c] = (_Float16)bo1;
    EB[(size_t)(i0+2)*128 + c] = (_Float16)eo2;
    EB[(size_t)(i0+2)*128 + 64 + c] = (_Float16)bo2;
    EB[(size_t)(i0+3)*128 + c] = (_Float16)eo3;
    EB[(size_t)(i0+3)*128 + 64 + c] = (_Float16)bo3;
    AD[(size_t)(i0+0)*128 + c] = (_Float16)ao0;
    AD[(size_t)(i0+0)*128 + 64 + c] = (_Float16)(do0 + bc);
    AD[(size_t)(i0+1)*128 + c] = (_Float16)ao1;
    AD[(size_t)(i0+1)*128 + 64 + c] = (_Float16)(do1 + bc);
    AD[(size_t)(i0+2)*128 + c] = (_Float16)ao2;
    AD[(size_t)(i0+2)*128 + 64 + c] = (_Float16)(do2 + bc);
    AD[(size_t)(i0+3)*128 + c] = (_Float16)ao3;
    AD[(size_t)(i0+3)*128 + 64 + c] = (_Float16)(do3 + bc);
}

// ---------------- NEW: pure streaming edge-GEMM  ce = e . WC  (f16) --------
// Linear grid over edges (no CSR), 256 edges/block, 4 tiles/wave. Validated
// MFMA fragment path + stride-68 transpose. No gathers, no atomics.
__global__ __launch_bounds__(256) void gemm_k(int l,
        const _Float16* __restrict__ e, _Float16* __restrict__ ce,
        const unsigned short* __restrict__ WBf){
    __shared__ short WAs[4096];            // 8 KB  WC B-fragments (f16)
    __shared__ float T[4][16*68];          // 17.4 KB out-transpose

    int t = threadIdx.x, c = t & 63, w = t >> 6;
    int r16 = c & 15, kb = c >> 4;

    { // stage B-fragments (2048 u32, coalesced) into LDS
        const unsigned* wsrc = (const unsigned*)(WBf + (l << 12));
        unsigned* wdst = (unsigned*)WAs;
        for (int idx=t; idx<2048; idx+=256) wdst[idx] = wsrc[idx];
    }
    __syncthreads();

    float* Tw = T[w];
    const hfrag* BF = ((const hfrag*)WAs) + c;           // frag f at BF[f*64]

    #pragma unroll 1
    for (int it=0; it<4; it++){
        int pt = blockIdx.x*256 + (w<<4) + (it<<6);
        const _Float16* ea = e + (size_t)(pt + r16)*64 + kb*8;
        hfrag a0v = *(const hfrag*)(ea);
        hfrag a1v = *(const hfrag*)(ea + 32);

        facc ac0 = {0.f,0.f,0.f,0.f}, ac1 = {0.f,0.f,0.f,0.f};
        facc ac2 = {0.f,0.f,0.f,0.f}, ac3 = {0.f,0.f,0.f,0.f};
        {
            hfrag Bx = BF[0*64], By = BF[2*64];
            ac0 = __builtin_amdgcn_mfma_f32_16x16x32_f16(a0v, Bx, ac0, 0, 0, 0);
            Bx = BF[4*64];
            ac1 = __builtin_amdgcn_mfma_f32_16x16x32_f16(a0v, By, ac1, 0, 0, 0);
            By = BF[6*64];
            ac2 = __builtin_amdgcn_mfma_f32_16x16x32_f16(a0v, Bx, ac2, 0, 0, 0);
            Bx = BF[1*64];
            ac3 = __builtin_amdgcn_mfma_f32_16x16x32_f16(a0v, By, ac3, 0, 0, 0);
            By = BF[3*64];
            ac0 = __builtin_amdgcn_mfma_f32_16x16x32_f16(a1v, Bx, ac0, 0, 0, 0);
            Bx = BF[5*64];
            ac1 = __builtin_amdgcn_mfma_f32_16x16x32_f16(a1v, By, ac1, 0, 0, 0);
            By = BF[7*64];
            ac2 = __builtin_amdgcn_mfma_f32_16x16x32_f16(a1v, Bx, ac2, 0, 0, 0);
            ac3 = __builtin_amdgcn_mfma_f32_16x16x32_f16(a1v, By, ac3, 0, 0, 0);
        }

        // acc -> T (C/D layout: row=(kb*4+r), col=ct*16+r16), stride 68
        #define TA(ct) Tw[(kb*4+0)*68 + ct*16 + r16] = ac##ct[0]; \
                       Tw[(kb*4+1)*68 + ct*16 + r16] = ac##ct[1]; \
                       Tw[(kb*4+2)*68 + ct*16 + r16] = ac##ct[2]; \
                       Tw[(kb*4+3)*68 + ct*16 + r16] = ac##ct[3];
        TA(0) TA(1) TA(2) TA(3)
        #undef TA

        _Float16* cp = ce + (size_t)pt*64 + c;
        #define ST(q) cp[q*64] = (_Float16)Tw[q*68 + c];
        E16(ST)
        #undef ST
    }
}

// ---------------- NEW: gather-gate-scatter (no MFMA, tiny LDS) -------------
// 8 nodes/block, 8 edges per wave-iter. LDS 8 KB -> 8 blocks/CU (wave cap,
// ~100% occupancy). Reads ce rows contiguously; EB gathers are f16 (half the
// line traffic). Gate math and LDS num/den atomics unchanged from R13.
__global__ __launch_bounds__(256) void gate_k(int l,
        _Float16* __restrict__ e, float* __restrict__ h,
        const _Float16* __restrict__ ce,
        const _Float16* __restrict__ EB, const _Float16* __restrict__ AD,
        const int* __restrict__ meta,
        const int* __restrict__ row_start){
    __shared__ float DhL[512];             // 2 KB
    __shared__ float ndN[512], ndD[512];   // 4 KB

    int t = threadIdx.x, c = t & 63, w = t >> 6;
    int i0 = blockIdx.x * 8;

    for (int idx=t; idx<512; idx+=256){ ndN[idx]=0.0f; ndD[idx]=0.0f; }

    float ah0 = (float)AD[(size_t)(i0+w)*128 + c];
    float ah1 = (float)AD[(size_t)(i0+w+4)*128 + c];
    #pragma unroll
    for (int rep=0; rep<2; rep++){
        int idx = t + rep*256;
        int n = idx >> 6, cc = idx & 63;
        DhL[idx] = (float)AD[(size_t)(i0+n)*128 + 64 + cc];
    }
    __syncthreads();

    int p0 = row_start[i0], pend = row_start[i0+8];
    const _Float16* ebB = EB + c;          // lane base: Eh at src*128, Bh +64

    for (int pt = p0 + (w << 3); pt < pend; pt += 32){
        int nv = pend - pt; if (nv > 8) nv = 8;

        const int* mp = meta + __builtin_amdgcn_readfirstlane(pt);
        #define LM(q) unsigned m##q = (unsigned)mp[q];
        E8(LM)
        #undef LM

        // gathers (f16, 2 lines/edge)
        #define DG(q) float ehv##q, bhv##q;
        E8(DG)
        #undef DG
        #define LG(q) { unsigned off = (m##q & 0xffffu) << 7; \
                        ehv##q = (float)ebB[off]; \
                        bhv##q = (float)ebB[off + 64]; }
        E8(LG)
        #undef LG

        // ce + e_old rows (contiguous f16)
        const _Float16* cp = ce + (size_t)pt*64 + c;
        const _Float16* ep = e  + (size_t)pt*64 + c;
        #define LC(q) float cv##q = (float)cp[q*64]; float pe##q = (float)ep[q*64];
        E8(LC)
        #undef LC

        #define GT(q) if (q < nv){ \
            int n = (int)(m##q >> 16); \
            float ehat = cv##q + DhL[n*64+c] + ehv##q; \
            float sig = 1.0f/(1.0f + __expf(-ehat)); \
            atomicAdd(&ndN[n*64+c], sig * bhv##q); \
            atomicAdd(&ndD[n*64+c], sig); \
            e[(size_t)(pt+q)*64+c] = (_Float16)(pe##q + fmaxf(ehat, 0.0f)); }
        E8(GT)
        #undef GT
    }
    __syncthreads();   // drain all waves' LDS atomics

    // fused h update for the block's 8 nodes
    {
        float hv = h[(size_t)(i0+w)*64 + c];
        float val = ah0 + ndN[w*64+c]/(ndD[w*64+c] + 1e-6f);
        h[(size_t)(i0+w)*64 + c] = hv + fmaxf(val, 0.0f);
    }
    {
        int n = w + 4;
        float hv = h[(size_t)(i0+n)*64 + c];
        float val = ah1 + ndN[n*64+c]/(ndD[n*64+c] + 1e-6f);
        h[(size_t)(i0+n)*64 + c] = hv + fmaxf(val, 0.0f);
    }
}

// ---------------- MLP head: wave per node (validated) ----------------
__global__ __launch_bounds__(256) void head_k(const float* __restrict__ h,
        const float* __restrict__ W1, const float* __restrict__ b1,
        const float* __restrict__ W2, const float* __restrict__ b2,
        float* __restrict__ out){
    int t = threadIdx.x, c = t & 63;
    int i = blockIdx.x*4 + (t >> 6);
    float hv = h[(size_t)i*64 + c];
    float z0 = b1[c], z1 = b1[64+c];
    #pragma unroll 8
    for (int k=0;k<64;k++){
        float hk = __shfl(hv, k);
        z0 += hk * W1[k*128+c];
        z1 += hk * W1[k*128+64+c];
    }
    z0 = fmaxf(z0, 0.0f); z1 = fmaxf(z1, 0.0f);
    float o0 = z0*W2[c*2+0] + z1*W2[(64+c)*2+0];
    float o1 = z0*W2[c*2+1] + z1*W2[(64+c)*2+1];
    #pragma unroll
    for (int off=32; off; off>>=1){
        o0 += __shfl_xor(o0, off);
        o1 += __shfl_xor(o1, off);
    }
    if (c == 0){
        out[(size_t)i*2+0] = -1.2f*tanhf(o0 + b2[0]);
        out[(size_t)i*2+1] = -1.2f*tanhf(o1 + b2[1]);
    }
}

extern "C" void kernel_launch(void* const* d_in, const int* in_sizes, int n_in,
                              void* d_out, int out_size, void* d_ws, size_t ws_size,
                              hipStream_t stream){
    float* out = (float*)d_out;
    int fill_blocks = (out_size + 255) / 256;

    if (n_in != 14){
        fill_k<<<fill_blocks, 256, 0, stream>>>(out, out_size, 0.25f);
        return;
    }
    const int exp_sizes[14] = {300000, 1600000, 800000, 800000, 384, 64, 128, 64,
                               81920, 1280, 8192, 128, 256, 2};
    bool sizes_ok = (out_size == 100000);
    for (int i=0;i<14;i++) if (in_sizes[i] != exp_sizes[i]) sizes_ok = false;
    if (!sizes_ok){
        fill_k<<<fill_blocks, 256, 0, stream>>>(out, out_size, 0.5f);
        return;
    }

    // ---- ws layout, ~247 MB (<= 248.8 known-good) ----
    size_t need = 0;
    size_t o_flags = need; need += 16;
    size_t o_rs   = need; need += (size_t)NP*4;
    size_t o_cur  = need; need += (size_t)NP*4;
    size_t o_bsum = need; need += (size_t)NBLK*4;
    size_t o_boff = need; need += (size_t)NBLK*4;
    size_t o_Weh  = need; need += 384ull*4;
    size_t o_beh  = need; need += 64ull*4;
    size_t o_Wee  = need; need += 128ull*4;
    size_t o_bee  = need; need += 64ull*4;
    size_t o_Wl   = need; need += 81920ull*4;
    size_t o_bl   = need; need += 1280ull*4;
    size_t o_W1   = need; need += 8192ull*4;
    size_t o_b1   = need; need += 128ull*4;
    size_t o_W2   = need; need += 256ull*4;
    size_t o_b2   = need; need += 2ull*4;
    size_t o_WBf  = need; need += 16384ull*2;   // MFMA B-fragments, 4 layers
    need = (need + 255) & ~(size_t)255;
    size_t o_perm = need; need += (size_t)(NE+16)*4;   // perm, reused as meta
    need = (need + 255) & ~(size_t)255;
    size_t o_h    = need; need += (size_t)NN*64*4;
    size_t o_EB   = need; need += (size_t)NN*128*2;    // f16
    size_t o_AD   = need; need += (size_t)NN*128*2;    // f16
    need = (need + 255) & ~(size_t)255;
    size_t o_e    = need; need += (size_t)(NE+16)*64*2;  // f16 e, +16 rows pad
    need = (need + 255) & ~(size_t)255;
    size_t o_ce   = need; need += (size_t)(NE+16)*64*2;  // f16 ce
    if (ws_size < need){
        fill_k<<<fill_blocks, 256, 0, stream>>>(out, out_size, 0.75f);
        return;
    }

    char* p = (char*)d_ws;
    int*   flags = (int*)(p + o_flags);
    int*   row_start = (int*)(p + o_rs);
    int*   cursor    = (int*)(p + o_cur);
    int*   bsum = (int*)(p + o_bsum);
    int*   boff = (int*)(p + o_boff);
    float* Weh = (float*)(p + o_Weh);
    float* beh = (float*)(p + o_beh);
    float* Wee = (float*)(p + o_Wee);
    float* bee = (float*)(p + o_bee);
    float* Wlc = (float*)(p + o_Wl);
    float* blc = (float*)(p + o_bl);
    float* W1c = (float*)(p + o_W1);
    float* b1c = (float*)(p + o_b1);
    float* W2c = (float*)(p + o_W2);
    float* b2c = (float*)(p + o_b2);
    unsigned short* WBf = (unsigned short*)(p + o_WBf);
    int*   perm = (int*)(p + o_perm);       // reused as meta after einit
    float* h  = (float*)(p + o_h);
    _Float16* EB = (_Float16*)(p + o_EB);
    _Float16* AD = (_Float16*)(p + o_AD);
    _Float16* e  = (_Float16*)(p + o_e);
    _Float16* ce = (_Float16*)(p + o_ce);
    int* cnt = cursor;

    const int* src = (const int*)d_in[2];
    const int* dst = (const int*)d_in[3];

    probe_f_k<<<1, 256, 0, stream>>>((const unsigned short*)d_in[0], flags);
    probe_i_k<<<1, 256, 0, stream>>>(dst, flags);

    cvt_k<<<2, 256, 0, stream>>>(d_in[4], Weh, 384, flags);
    cvt_k<<<1, 256, 0, stream>>>(d_in[5], beh, 64, flags);
    cvt_k<<<1, 256, 0, stream>>>(d_in[6], Wee, 128, flags);
    cvt_k<<<1, 256, 0, stream>>>(d_in[7], bee, 64, flags);
    cvt_k<<<(81920+255)/256, 256, 0, stream>>>(d_in[8], Wlc, 81920, flags);
    cvt_k<<<5, 256, 0, stream>>>(d_in[9], blc, 1280, flags);
    cvt_k<<<32, 256, 0, stream>>>(d_in[10], W1c, 8192, flags);
    cvt_k<<<1, 256, 0, stream>>>(d_in[11], b1c, 128, flags);
    cvt_k<<<1, 256, 0, stream>>>(d_in[12], W2c, 256, flags);
    cvt_k<<<1, 256, 0, stream>>>(d_in[13], b2c, 2, flags);

    packb_k<<<64, 256, 0, stream>>>(Wlc, WBf);

    embed_k<<<NN/4, 256, 0, stream>>>(d_in[0], Weh, beh, h, flags);

    zero_cnt_k<<<NBLK, 256, 0, stream>>>(cnt);
    hist_k<<<NE/256, 256, 0, stream>>>(dst, cnt, flags);
    scan1_k<<<NBLK, 256, 0, stream>>>(cnt, row_start, bsum);
    scan2_k<<<1, 256, 0, stream>>>(bsum, boff);
    scan3_k<<<NBLK, 256, 0, stream>>>(row_start, boff, cursor);
    scatter_k<<<NE/256, 256, 0, stream>>>(dst, cursor, perm, flags);

    // einit also builds meta[] in-place over perm[]
    einit_k<<<NE*64/256, 256, 0, stream>>>(d_in[1], Wee, bee, perm, perm, src, dst,
                                           e, flags);

    for (int l=0; l<4; l++){
        node4_k<<<NN/16, 256, 0, stream>>>(l, h, Wlc, blc, EB, AD);
        gemm_k<<<NE/256, 256, 0, stream>>>(l, e, ce, WBf);
        gate_k<<<NN/8, 256, 0, stream>>>(l, e, h, ce, EB, AD, perm, row_start);
    }
    head_k<<<NN/4, 256, 0, stream>>>(h, W1c, b1c, W2c, b2c, out);
}

// Round 16
// 944.280 us; speedup vs baseline: 3.0096x; 3.0096x over previous
//
#include <hip/hip_runtime.h>
#include <hip/hip_bf16.h>
#include <hip/hip_fp16.h>

#define NN 50000
#define NE 800000
#define NP 50176          // 196*256 padded node count for scan
#define NBLK 196

#define E8(M)  M(0) M(1) M(2) M(3) M(4) M(5) M(6) M(7)
#define E8B(M) M(8) M(9) M(10) M(11) M(12) M(13) M(14) M(15)
#define E16(M) E8(M) E8B(M)

typedef __attribute__((ext_vector_type(8))) _Float16 hfrag;  // 8 f16 (4 VGPR)
typedef __attribute__((ext_vector_type(4))) float facc;      // 4 fp32 acc

__device__ __forceinline__ float us2f_bf16(unsigned short u){
    unsigned v = ((unsigned)u) << 16; float f; __builtin_memcpy(&f, &v, 4); return f;
}
__device__ __forceinline__ float us2f_f16(unsigned short u){
    __half h; __builtin_memcpy(&h, &u, 2); return __half2float(h);
}
// mode: 0=bf16, 1=f16, 2=fp32
__device__ __forceinline__ float ldf3(const void* p, size_t i, int mode){
    if (mode == 2) return ((const float*)p)[i];
    unsigned short u = ((const unsigned short*)p)[i];
    return (mode == 0) ? us2f_bf16(u) : us2f_f16(u);
}
__device__ __forceinline__ int ldi(const int* p, size_t j, int i64){
    return i64 ? p[2*j] : p[j];
}
__device__ __forceinline__ unsigned packh2(float a, float b){
    _Float16 ha = (_Float16)a, hb = (_Float16)b;
    unsigned short ua, ub;
    __builtin_memcpy(&ua, &ha, 2); __builtin_memcpy(&ub, &hb, 2);
    return (unsigned)ua | ((unsigned)ub << 16);
}
// broadcast lane l's value via v_readlane (VALU pipe -> SGPR, no LDS)
__device__ __forceinline__ float rl(float v, int l){
    return __uint_as_float(__builtin_amdgcn_readlane(__float_as_uint(v), l));
}

// ---------------- sentinel fill (fp32 output) ----------------
__global__ void fill_k(float* __restrict__ out, int n, float cval){
    int i = blockIdx.x*256 + threadIdx.x;
    if (i < n) out[i] = cval;
}

// ---------------- probes (validated) ----------------
__global__ void probe_f_k(const unsigned short* __restrict__ hf, int* __restrict__ flags){
    __shared__ int cnt;
    if (threadIdx.x == 0) cnt = 0;
    __syncthreads();
    int c = 0;
    for (int idx = threadIdx.x; idx < 2048; idx += 256){
        int ex = (hf[2*idx] >> 7) & 0xFF;
        if (ex >= 118 && ex <= 131) c++;
    }
    atomicAdd(&cnt, c);
    __syncthreads();
    if (threadIdx.x == 0){
        int inb = cnt;
        int mode;
        if (inb >= 1536)      mode = 0;     // bf16
        else if (inb <= 205)  mode = 2;     // fp32
        else                  mode = 1;     // f16
        flags[0] = mode;
    }
}
__global__ void probe_i_k(const int* __restrict__ d, int* __restrict__ flags){
    __shared__ int nz;
    if (threadIdx.x == 0) nz = 0;
    __syncthreads();
    int c = 0;
    for (int idx = threadIdx.x; idx < 2048; idx += 256){
        if (d[2*idx + 1] != 0) c++;
    }
    atomicAdd(&nz, c);
    __syncthreads();
    if (threadIdx.x == 0) flags[1] = (nz < 100) ? 1 : 0;
}

// ---------------- weight conversion ----------------
__global__ void cvt_k(const void* __restrict__ src, float* __restrict__ dst, int n,
                      const int* __restrict__ flags){
    int m = flags[0];
    int i = blockIdx.x*256 + threadIdx.x;
    if (i < n) dst[i] = ldf3(src, i, m);
}

// ---------------- pack per-layer WC into MFMA B-fragment layout (f16) ------
// For 16x16x32 (f16, same layout as validated bf16): lane holds B[k][col],
// k = s*32 + (lane>>4)*8 + j, col = ct*16 + (lane&15).
// WBf[l*4096 + (ct*2+s)*512 + lane*8 + j]
__global__ void packb_k(const float* __restrict__ Wlc, unsigned short* __restrict__ WBf){
    int i = blockIdx.x*256 + threadIdx.x;     // 0..16383
    int l = i >> 12, r = i & 4095;
    int ct2s = r >> 9, lane = (r >> 3) & 63, j = r & 7;
    int ct = ct2s >> 1, s = ct2s & 1;
    int k  = s*32 + (lane >> 4)*8 + j;
    int col = ct*16 + (lane & 15);
    const float* WC = Wlc + (size_t)l*5*4096 + 4*4096;
    _Float16 hv = (_Float16)WC[k*64 + col];   // RNE
    unsigned short u; __builtin_memcpy(&u, &hv, 2);
    WBf[i] = u;
}

// ---------------- node embedding: wave per node (validated) ----------------
__global__ __launch_bounds__(256) void embed_k(const void* __restrict__ hf,
        const float* __restrict__ W, const float* __restrict__ b,
        float* __restrict__ h, const int* __restrict__ flags){
    int f = flags[0];
    int t = threadIdx.x, c = t & 63;
    int i = blockIdx.x*4 + (t >> 6);
    float a = b[c];
    #pragma unroll
    for (int k=0;k<6;k++) a += ldf3(hf, (size_t)i*6+k, f) * W[k*64+c];
    h[(size_t)i*64+c] = a;
}

// ---------------- CSR build (counting sort by dst, validated) ----------------
__global__ void zero_cnt_k(int* __restrict__ cnt){
    int i = blockIdx.x*256 + threadIdx.x;
    cnt[i] = 0;
}
__global__ void hist_k(const int* __restrict__ dst, int* __restrict__ cnt,
                       const int* __restrict__ flags){
    int i64 = flags[1];
    int j = blockIdx.x*256 + threadIdx.x;
    atomicAdd(&cnt[ldi(dst, j, i64)], 1);
}
__global__ void scan1_k(const int* __restrict__ cnt, int* __restrict__ row_start,
                        int* __restrict__ bsum){
    __shared__ int s[256];
    int t = threadIdx.x;
    int i = blockIdx.x*256 + t;
    int v = cnt[i];
    s[t] = v; __syncthreads();
    #pragma unroll
    for (int off=1; off<256; off<<=1){
        int add = (t>=off) ? s[t-off] : 0;
        __syncthreads();
        s[t] += add;
        __syncthreads();
    }
    row_start[i] = s[t] - v;
    if (t==255) bsum[blockIdx.x] = s[255];
}
__global__ void scan2_k(const int* __restrict__ bsum, int* __restrict__ boff){
    __shared__ int s[256];
    int t = threadIdx.x;
    int v = (t < NBLK) ? bsum[t] : 0;
    s[t] = v; __syncthreads();
    #pragma unroll
    for (int off=1; off<256; off<<=1){
        int add = (t>=off) ? s[t-off] : 0;
        __syncthreads();
        s[t] += add;
        __syncthreads();
    }
    if (t < NBLK) boff[t] = s[t] - v;
}
__global__ void scan3_k(int* __restrict__ row_start, const int* __restrict__ boff,
                        int* __restrict__ cursor){
    int i = blockIdx.x*256 + threadIdx.x;
    int x = row_start[i] + boff[blockIdx.x];
    row_start[i] = x;
    cursor[i] = x;
}
__global__ void scatter_k(const int* __restrict__ dst, int* __restrict__ cursor,
                          int* __restrict__ perm, const int* __restrict__ flags){
    int i64 = flags[1];
    int j = blockIdx.x*256 + threadIdx.x;
    int d = ldi(dst, j, i64);
    int p = atomicAdd(&cursor[d], 1);
    perm[p] = j;
}

// ---------------- e init (f16, CSR order) + fused meta build ----------------
// meta[p] = src16 | ((dst&7) << 16), written into perm's own storage.
__global__ void einit_k(const void* __restrict__ ef, const float* __restrict__ Wee,
                        const float* __restrict__ bee, const int* perm,
                        int* meta, const int* __restrict__ src,
                        const int* __restrict__ dst,
                        _Float16* __restrict__ e, const int* __restrict__ flags){
    int f = flags[0], i64 = flags[1];
    int tid = blockIdx.x*256 + threadIdx.x;
    int c = tid & 63, p = tid >> 6;
    int j = perm[p];
    float f0 = ldf3(ef, (size_t)j*2+0, f), f1 = ldf3(ef, (size_t)j*2+1, f);
    e[(size_t)p*64+c] = (_Float16)(bee[c] + f0*Wee[c] + f1*Wee[64+c]);
    if (c == 0)
        meta[p] = (ldi(src, j, i64) & 0xffff) | ((ldi(dst, j, i64) & 7) << 16);
    if (p < 16 && c == 1) meta[NE + p] = 0;
}

// ---------------- per-layer node transforms: 4 nodes per WAVE --------------
// EBi[i*64+c] = pack(f16 Eh, f16 Bh)  (one dword gather per edge in gg_k)
// AD16[i][0:64)=Ah, [64:128)=Dh+bC.
__global__ __launch_bounds__(256) void node4_k(int l, const float* __restrict__ h,
        const float* __restrict__ Wlc, const float* __restrict__ blc,
        unsigned* __restrict__ EBi, _Float16* __restrict__ AD){
    int t = threadIdx.x, c = t & 63, w = t >> 6;
    int i0 = blockIdx.x*16 + w*4;
    const float* WA = Wlc + (size_t)l*5*4096;
    const float* WB = WA + 4096;
    const float* WD = WA + 2*4096;
    const float* WE = WA + 3*4096;
    const float* bm = blc + (size_t)l*320;
    float hv0 = h[(size_t)(i0+0)*64 + c];
    float hv1 = h[(size_t)(i0+1)*64 + c];
    float hv2 = h[(size_t)(i0+2)*64 + c];
    float hv3 = h[(size_t)(i0+3)*64 + c];
    float ba = bm[c], bb = bm[64+c], bd = bm[128+c], be = bm[192+c];
    float ao0=ba, ao1=ba, ao2=ba, ao3=ba;
    float bo0=bb, bo1=bb, bo2=bb, bo3=bb;
    float do0=bd, do1=bd, do2=bd, do3=bd;
    float eo0=be, eo1=be, eo2=be, eo3=be;
    #pragma unroll 8
    for (int k=0;k<64;k++){
        float wa = WA[k*64+c], wb = WB[k*64+c], wd = WD[k*64+c], we = WE[k*64+c];
        float h0 = rl(hv0,k), h1 = rl(hv1,k), h2 = rl(hv2,k), h3 = rl(hv3,k);
        ao0 = fmaf(h0, wa, ao0); ao1 = fmaf(h1, wa, ao1);
        ao2 = fmaf(h2, wa, ao2); ao3 = fmaf(h3, wa, ao3);
        bo0 = fmaf(h0, wb, bo0); bo1 = fmaf(h1, wb, bo1);
        bo2 = fmaf(h2, wb, bo2); bo3 = fmaf(h3, wb, bo3);
        do0 = fmaf(h0, wd, do0); do1 = fmaf(h1, wd, do1);
        do2 = fmaf(h2, wd, do2); do3 = fmaf(h3, wd, do3);
        eo0 = fmaf(h0, we, eo0); eo1 = fmaf(h1, we, eo1);
        eo2 = fmaf(h2, we, eo2); eo3 = fmaf(h3, we, eo3);
    }
    float bc = bm[256+c];
    EBi[(size_t)(i0+0)*64 + c] = packh2(eo0, bo0);
    EBi[(size_t)(i0+1)*64 + c] = packh2(eo1, bo1);
    EBi[(size_t)(i0+2)*64 + c] = packh2(eo2, bo2);
    EBi[(size_t)(i0+3)*64 + c] = packh2(eo3, bo3);
    AD[(size_t)(i0+0)*128 + c] = (_Float16)ao0;
    AD[(size_t)(i0+0)*128 + 64 + c] = (_Float16)(do0 + bc);
    AD[(size_t)(i0+1)*128 + c] = (_Float16)ao1;
    AD[(size_t)(i0+1)*128 + 64 + c] = (_Float16)(do1 + bc);
    AD[(size_t)(i0+2)*128 + c] = (_Float16)ao2;
    AD[(size_t)(i0+2)*128 + 64 + c] = (_Float16)(do2 + bc);
    AD[(size_t)(i0+3)*128 + c] = (_Float16)ao3;
    AD[(size_t)(i0+3)*128 + 64 + c] = (_Float16)(do3 + bc);
}

// ---------------- fused MFMA-GEMM-gate-REGISTER-reduce: 8 nodes per block ---
// R16 = R15 with the macro hygiene fixed (LG/GT defined once, used for both
// batches). Each wave owns TWO CONTIGUOUS nodes (local 2w, 2w+1 -> contiguous
// CSR range), accumulating num/den in 4 REGISTERS selected by (dst&7)&1.
// Deleted: ndN/ndD, DhL, all LDS atomics, the closing barrier. Gathers
// halved: one dword EBi[src] yields (Eh,Bh). MFMA path / transpose / meta
// s_load unchanged (validated).
__global__ __launch_bounds__(256) void gg_k(int l,
        _Float16* __restrict__ e, float* __restrict__ h,
        const unsigned* __restrict__ EBi, const _Float16* __restrict__ AD,
        const int* __restrict__ meta,
        const int* __restrict__ row_start,
        const unsigned short* __restrict__ WBf){
    __shared__ short WAs[4096];            // 8 KB  WC B-fragments (f16)
    __shared__ float T[4][16*68];          // 17.4 KB out-transpose

    int t = threadIdx.x, c = t & 63, w = t >> 6;
    int r16 = c & 15, kb = c >> 4;
    int i0 = blockIdx.x * 8;

    { // stage B-fragments (2048 u32, coalesced) into LDS
        const unsigned* wsrc = (const unsigned*)(WBf + (l << 12));
        unsigned* wdst = (unsigned*)WAs;
        for (int idx=t; idx<2048; idx+=256) wdst[idx] = wsrc[idx];
    }

    int n0 = i0 + 2*w;                     // wave owns nodes n0, n0+1
    float ah0 = (float)AD[(size_t)n0*128 + c];
    float ah1 = (float)AD[(size_t)(n0+1)*128 + c];
    float dh0 = (float)AD[(size_t)n0*128 + 64 + c];
    float dh1 = (float)AD[(size_t)(n0+1)*128 + 64 + c];
    int rsA = row_start[n0], rsC = row_start[n0+2];
    __syncthreads();                       // WAs ready

    float nm0 = 0.f, dn0 = 0.f, nm1 = 0.f, dn1 = 0.f;
    float* Tw = T[w];
    const hfrag* BF = ((const hfrag*)WAs) + c;   // frag f at BF[f*64]

    for (int pt = rsA; pt < rsC; pt += 16){
        int nv = rsC - pt; if (nv > 16) nv = 16;
        const int* mp = meta + __builtin_amdgcn_readfirstlane(pt);

        // A-fragment rows straight from global as f16 (validated mapping)
        const _Float16* ea = e + (size_t)(pt + r16)*64 + kb*8;
        hfrag a0v = *(const hfrag*)(ea);
        hfrag a1v = *(const hfrag*)(ea + 32);

        facc ac0 = {0.f,0.f,0.f,0.f}, ac1 = {0.f,0.f,0.f,0.f};
        facc ac2 = {0.f,0.f,0.f,0.f}, ac3 = {0.f,0.f,0.f,0.f};
        {
            hfrag Bx = BF[0*64], By = BF[2*64];
            ac0 = __builtin_amdgcn_mfma_f32_16x16x32_f16(a0v, Bx, ac0, 0, 0, 0);
            Bx = BF[4*64];
            ac1 = __builtin_amdgcn_mfma_f32_16x16x32_f16(a0v, By, ac1, 0, 0, 0);
            By = BF[6*64];
            ac2 = __builtin_amdgcn_mfma_f32_16x16x32_f16(a0v, Bx, ac2, 0, 0, 0);
            Bx = BF[1*64];
            ac3 = __builtin_amdgcn_mfma_f32_16x16x32_f16(a0v, By, ac3, 0, 0, 0);
            By = BF[3*64];
            ac0 = __builtin_amdgcn_mfma_f32_16x16x32_f16(a1v, Bx, ac0, 0, 0, 0);
            Bx = BF[5*64];
            ac1 = __builtin_amdgcn_mfma_f32_16x16x32_f16(a1v, By, ac1, 0, 0, 0);
            By = BF[7*64];
            ac2 = __builtin_amdgcn_mfma_f32_16x16x32_f16(a1v, Bx, ac2, 0, 0, 0);
            ac3 = __builtin_amdgcn_mfma_f32_16x16x32_f16(a1v, By, ac3, 0, 0, 0);
        }

        // acc -> T (C/D layout: row=(kb*4+r), col=ct*16+r16), stride 68
        #define TA(ct) Tw[(kb*4+0)*68 + ct*16 + r16] = ac##ct[0]; \
                       Tw[(kb*4+1)*68 + ct*16 + r16] = ac##ct[1]; \
                       Tw[(kb*4+2)*68 + ct*16 + r16] = ac##ct[2]; \
                       Tw[(kb*4+3)*68 + ct*16 + r16] = ac##ct[3];
        TA(0) TA(1) TA(2) TA(3)
        #undef TA

        const _Float16* ep = e + (size_t)pt*64 + c;

        // meta + single-dword gathers + gate with register reduce
        #define LM(q) unsigned m##q = (unsigned)mp[q];
        #define LG(q) unsigned g##q = EBi[(size_t)(m##q & 0xffffu)*64 + c];
        #define GT(q) if (q < nv){ \
            int hi = (int)((m##q >> 16) & 1u); \
            float ehat = Tw[q*68 + c] + (hi ? dh1 : dh0) \
                       + us2f_f16((unsigned short)(g##q & 0xffffu)); \
            float sig = 1.0f/(1.0f + __expf(-ehat)); \
            float nb = sig * us2f_f16((unsigned short)(g##q >> 16)); \
            nm0 += hi ? 0.0f : nb;  nm1 += hi ? nb : 0.0f; \
            dn0 += hi ? 0.0f : sig; dn1 += hi ? sig : 0.0f; \
            e[(size_t)(pt+q)*64+c] = (_Float16)((float)ep[q*64] + fmaxf(ehat, 0.0f)); }

        // batch0
        E8(LM)
        E8(LG)
        E8(GT)
        // batch1
        E8B(LM)
        E8B(LG)
        E8B(GT)

        #undef LM
        #undef LG
        #undef GT
    }

    // per-wave h update for its 2 nodes (no barrier needed)
    {
        float hv = h[(size_t)n0*64 + c];
        h[(size_t)n0*64 + c] = hv + fmaxf(ah0 + nm0/(dn0 + 1e-6f), 0.0f);
    }
    {
        float hv = h[(size_t)(n0+1)*64 + c];
        h[(size_t)(n0+1)*64 + c] = hv + fmaxf(ah1 + nm1/(dn1 + 1e-6f), 0.0f);
    }
}

// ---------------- MLP head: wave per node (validated) ----------------
__global__ __launch_bounds__(256) void head_k(const float* __restrict__ h,
        const float* __restrict__ W1, const float* __restrict__ b1,
        const float* __restrict__ W2, const float* __restrict__ b2,
        float* __restrict__ out){
    int t = threadIdx.x, c = t & 63;
    int i = blockIdx.x*4 + (t >> 6);
    float hv = h[(size_t)i*64 + c];
    float z0 = b1[c], z1 = b1[64+c];
    #pragma unroll 8
    for (int k=0;k<64;k++){
        float hk = __shfl(hv, k);
        z0 += hk * W1[k*128+c];
        z1 += hk * W1[k*128+64+c];
    }
    z0 = fmaxf(z0, 0.0f); z1 = fmaxf(z1, 0.0f);
    float o0 = z0*W2[c*2+0] + z1*W2[(64+c)*2+0];
    float o1 = z0*W2[c*2+1] + z1*W2[(64+c)*2+1];
    #pragma unroll
    for (int off=32; off; off>>=1){
        o0 += __shfl_xor(o0, off);
        o1 += __shfl_xor(o1, off);
    }
    if (c == 0){
        out[(size_t)i*2+0] = -1.2f*tanhf(o0 + b2[0]);
        out[(size_t)i*2+1] = -1.2f*tanhf(o1 + b2[1]);
    }
}

extern "C" void kernel_launch(void* const* d_in, const int* in_sizes, int n_in,
                              void* d_out, int out_size, void* d_ws, size_t ws_size,
                              hipStream_t stream){
    float* out = (float*)d_out;
    int fill_blocks = (out_size + 255) / 256;

    if (n_in != 14){
        fill_k<<<fill_blocks, 256, 0, stream>>>(out, out_size, 0.25f);
        return;
    }
    const int exp_sizes[14] = {300000, 1600000, 800000, 800000, 384, 64, 128, 64,
                               81920, 1280, 8192, 128, 256, 2};
    bool sizes_ok = (out_size == 100000);
    for (int i=0;i<14;i++) if (in_sizes[i] != exp_sizes[i]) sizes_ok = false;
    if (!sizes_ok){
        fill_k<<<fill_blocks, 256, 0, stream>>>(out, out_size, 0.5f);
        return;
    }

    // ---- ws layout, ~146 MB (well under known-good) ----
    size_t need = 0;
    size_t o_flags = need; need += 16;
    size_t o_rs   = need; need += (size_t)NP*4;
    size_t o_cur  = need; need += (size_t)NP*4;
    size_t o_bsum = need; need += (size_t)NBLK*4;
    size_t o_boff = need; need += (size_t)NBLK*4;
    size_t o_Weh  = need; need += 384ull*4;
    size_t o_beh  = need; need += 64ull*4;
    size_t o_Wee  = need; need += 128ull*4;
    size_t o_bee  = need; need += 64ull*4;
    size_t o_Wl   = need; need += 81920ull*4;
    size_t o_bl   = need; need += 1280ull*4;
    size_t o_W1   = need; need += 8192ull*4;
    size_t o_b1   = need; need += 128ull*4;
    size_t o_W2   = need; need += 256ull*4;
    size_t o_b2   = need; need += 2ull*4;
    size_t o_WBf  = need; need += 16384ull*2;   // MFMA B-fragments, 4 layers
    need = (need + 255) & ~(size_t)255;
    size_t o_perm = need; need += (size_t)(NE+16)*4;   // perm, reused as meta
    need = (need + 255) & ~(size_t)255;
    size_t o_h    = need; need += (size_t)NN*64*4;
    size_t o_EB   = need; need += (size_t)NN*64*4;     // EBi u32 (Eh|Bh f16)
    size_t o_AD   = need; need += (size_t)NN*128*2;    // f16
    need = (need + 255) & ~(size_t)255;
    size_t o_e    = need; need += (size_t)(NE+16)*64*2;  // f16 e, +16 rows pad
    if (ws_size < need){
        fill_k<<<fill_blocks, 256, 0, stream>>>(out, out_size, 0.75f);
        return;
    }

    char* p = (char*)d_ws;
    int*   flags = (int*)(p + o_flags);
    int*   row_start = (int*)(p + o_rs);
    int*   cursor    = (int*)(p + o_cur);
    int*   bsum = (int*)(p + o_bsum);
    int*   boff = (int*)(p + o_boff);
    float* Weh = (float*)(p + o_Weh);
    float* beh = (float*)(p + o_beh);
    float* Wee = (float*)(p + o_Wee);
    float* bee = (float*)(p + o_bee);
    float* Wlc = (float*)(p + o_Wl);
    float* blc = (float*)(p + o_bl);
    float* W1c = (float*)(p + o_W1);
    float* b1c = (float*)(p + o_b1);
    float* W2c = (float*)(p + o_W2);
    float* b2c = (float*)(p + o_b2);
    unsigned short* WBf = (unsigned short*)(p + o_WBf);
    int*   perm = (int*)(p + o_perm);       // reused as meta after einit
    float* h  = (float*)(p + o_h);
    unsigned* EBi = (unsigned*)(p + o_EB);
    _Float16* AD = (_Float16*)(p + o_AD);
    _Float16* e  = (_Float16*)(p + o_e);
    int* cnt = cursor;

    const int* src = (const int*)d_in[2];
    const int* dst = (const int*)d_in[3];

    probe_f_k<<<1, 256, 0, stream>>>((const unsigned short*)d_in[0], flags);
    probe_i_k<<<1, 256, 0, stream>>>(dst, flags);

    cvt_k<<<2, 256, 0, stream>>>(d_in[4], Weh, 384, flags);
    cvt_k<<<1, 256, 0, stream>>>(d_in[5], beh, 64, flags);
    cvt_k<<<1, 256, 0, stream>>>(d_in[6], Wee, 128, flags);
    cvt_k<<<1, 256, 0, stream>>>(d_in[7], bee, 64, flags);
    cvt_k<<<(81920+255)/256, 256, 0, stream>>>(d_in[8], Wlc, 81920, flags);
    cvt_k<<<5, 256, 0, stream>>>(d_in[9], blc, 1280, flags);
    cvt_k<<<32, 256, 0, stream>>>(d_in[10], W1c, 8192, flags);
    cvt_k<<<1, 256, 0, stream>>>(d_in[11], b1c, 128, flags);
    cvt_k<<<1, 256, 0, stream>>>(d_in[12], W2c, 256, flags);
    cvt_k<<<1, 256, 0, stream>>>(d_in[13], b2c, 2, flags);

    packb_k<<<64, 256, 0, stream>>>(Wlc, WBf);

    embed_k<<<NN/4, 256, 0, stream>>>(d_in[0], Weh, beh, h, flags);

    zero_cnt_k<<<NBLK, 256, 0, stream>>>(cnt);
    hist_k<<<NE/256, 256, 0, stream>>>(dst, cnt, flags);
    scan1_k<<<NBLK, 256, 0, stream>>>(cnt, row_start, bsum);
    scan2_k<<<1, 256, 0, stream>>>(bsum, boff);
    scan3_k<<<NBLK, 256, 0, stream>>>(row_start, boff, cursor);
    scatter_k<<<NE/256, 256, 0, stream>>>(dst, cursor, perm, flags);

    // einit also builds meta[] in-place over perm[]
    einit_k<<<NE*64/256, 256, 0, stream>>>(d_in[1], Wee, bee, perm, perm, src, dst,
                                           e, flags);

    for (int l=0; l<4; l++){
        node4_k<<<NN/16, 256, 0, stream>>>(l, h, Wlc, blc, EBi, AD);
        gg_k<<<NN/8, 256, 0, stream>>>(l, e, h, EBi, AD, perm, row_start, WBf);
    }
    head_k<<<NN/4, 256, 0, stream>>>(h, W1c, b1c, W2c, b2c, out);
}

// Round 17
// 851.968 us; speedup vs baseline: 3.3357x; 1.1084x over previous
//
#include <hip/hip_runtime.h>
#include <hip/hip_bf16.h>
#include <hip/hip_fp16.h>

#define NN 50000
#define NE 800000
#define NP 50176          // 196*256 padded node count for scan
#define NBLK 196

#define E8(M)  M(0) M(1) M(2) M(3) M(4) M(5) M(6) M(7)
#define E8B(M) M(8) M(9) M(10) M(11) M(12) M(13) M(14) M(15)
#define E16(M) E8(M) E8B(M)

typedef __attribute__((ext_vector_type(8))) _Float16 hfrag;  // 8 f16 (4 VGPR)
typedef __attribute__((ext_vector_type(4))) float facc;      // 4 fp32 acc

__device__ __forceinline__ float us2f_bf16(unsigned short u){
    unsigned v = ((unsigned)u) << 16; float f; __builtin_memcpy(&f, &v, 4); return f;
}
__device__ __forceinline__ float us2f_f16(unsigned short u){
    __half h; __builtin_memcpy(&h, &u, 2); return __half2float(h);
}
// mode: 0=bf16, 1=f16, 2=fp32
__device__ __forceinline__ float ldf3(const void* p, size_t i, int mode){
    if (mode == 2) return ((const float*)p)[i];
    unsigned short u = ((const unsigned short*)p)[i];
    return (mode == 0) ? us2f_bf16(u) : us2f_f16(u);
}
__device__ __forceinline__ int ldi(const int* p, size_t j, int i64){
    return i64 ? p[2*j] : p[j];
}
__device__ __forceinline__ unsigned packh2(float a, float b){
    _Float16 ha = (_Float16)a, hb = (_Float16)b;
    unsigned short ua, ub;
    __builtin_memcpy(&ua, &ha, 2); __builtin_memcpy(&ub, &hb, 2);
    return (unsigned)ua | ((unsigned)ub << 16);
}
// broadcast lane l's value via v_readlane (VALU pipe -> SGPR, no LDS)
__device__ __forceinline__ float rl(float v, int l){
    return __uint_as_float(__builtin_amdgcn_readlane(__float_as_uint(v), l));
}

// ---------------- sentinel fill (fp32 output) ----------------
__global__ void fill_k(float* __restrict__ out, int n, float cval){
    int i = blockIdx.x*256 + threadIdx.x;
    if (i < n) out[i] = cval;
}

// ---------------- probes (validated) ----------------
__global__ void probe_f_k(const unsigned short* __restrict__ hf, int* __restrict__ flags){
    __shared__ int cnt;
    if (threadIdx.x == 0) cnt = 0;
    __syncthreads();
    int c = 0;
    for (int idx = threadIdx.x; idx < 2048; idx += 256){
        int ex = (hf[2*idx] >> 7) & 0xFF;
        if (ex >= 118 && ex <= 131) c++;
    }
    atomicAdd(&cnt, c);
    __syncthreads();
    if (threadIdx.x == 0){
        int inb = cnt;
        int mode;
        if (inb >= 1536)      mode = 0;     // bf16
        else if (inb <= 205)  mode = 2;     // fp32
        else                  mode = 1;     // f16
        flags[0] = mode;
    }
}
__global__ void probe_i_k(const int* __restrict__ d, int* __restrict__ flags){
    __shared__ int nz;
    if (threadIdx.x == 0) nz = 0;
    __syncthreads();
    int c = 0;
    for (int idx = threadIdx.x; idx < 2048; idx += 256){
        if (d[2*idx + 1] != 0) c++;
    }
    atomicAdd(&nz, c);
    __syncthreads();
    if (threadIdx.x == 0) flags[1] = (nz < 100) ? 1 : 0;
}

// ---------------- merged weight conversion (dst buffers contiguous in ws) ---
// segments: Weh[0,384) beh[384,448) Wee[448,576) bee[576,640) Wlc[640,82560)
// blc[82560,83840) W1[83840,92032) b1[92032,92160) W2[92160,92416) b2[,92418)
__global__ void cvtall_k(const void* s0, const void* s1, const void* s2,
        const void* s3, const void* s4, const void* s5, const void* s6,
        const void* s7, const void* s8, const void* s9,
        float* __restrict__ dst, const int* __restrict__ flags){
    int m = flags[0];
    int i = blockIdx.x*256 + threadIdx.x;
    if (i >= 92418) return;
    const void* s; int o;
    if      (i < 384)   { s=s0; o=0; }
    else if (i < 448)   { s=s1; o=384; }
    else if (i < 576)   { s=s2; o=448; }
    else if (i < 640)   { s=s3; o=576; }
    else if (i < 82560) { s=s4; o=640; }
    else if (i < 83840) { s=s5; o=82560; }
    else if (i < 92032) { s=s6; o=83840; }
    else if (i < 92160) { s=s7; o=92032; }
    else if (i < 92416) { s=s8; o=92160; }
    else                { s=s9; o=92416; }
    dst[i] = ldf3(s, (size_t)(i - o), m);
}

// ---------------- pack per-layer WC into MFMA B-fragment layout (f16) ------
// For 16x16x32 (f16, same layout as validated bf16): lane holds B[k][col],
// k = s*32 + (lane>>4)*8 + j, col = ct*16 + (lane&15).
// WBf[l*4096 + (ct*2+s)*512 + lane*8 + j]
__global__ void packb_k(const float* __restrict__ Wlc, unsigned short* __restrict__ WBf){
    int i = blockIdx.x*256 + threadIdx.x;     // 0..16383
    int l = i >> 12, r = i & 4095;
    int ct2s = r >> 9, lane = (r >> 3) & 63, j = r & 7;
    int ct = ct2s >> 1, s = ct2s & 1;
    int k  = s*32 + (lane >> 4)*8 + j;
    int col = ct*16 + (lane & 15);
    const float* WC = Wlc + (size_t)l*5*4096 + 4*4096;
    _Float16 hv = (_Float16)WC[k*64 + col];   // RNE
    unsigned short u; __builtin_memcpy(&u, &hv, 2);
    WBf[i] = u;
}

// ---------------- node embedding: wave per node (validated) ----------------
__global__ __launch_bounds__(256) void embed_k(const void* __restrict__ hf,
        const float* __restrict__ W, const float* __restrict__ b,
        float* __restrict__ h, const int* __restrict__ flags){
    int f = flags[0];
    int t = threadIdx.x, c = t & 63;
    int i = blockIdx.x*4 + (t >> 6);
    float a = b[c];
    #pragma unroll
    for (int k=0;k<6;k++) a += ldf3(hf, (size_t)i*6+k, f) * W[k*64+c];
    h[(size_t)i*64+c] = a;
}

// ---------------- CSR build (counting sort by dst, validated) ----------------
__global__ void zero_cnt_k(int* __restrict__ cnt){
    int i = blockIdx.x*256 + threadIdx.x;
    cnt[i] = 0;
}
__global__ void hist_k(const int* __restrict__ dst, int* __restrict__ cnt,
                       const int* __restrict__ flags){
    int i64 = flags[1];
    int j = blockIdx.x*256 + threadIdx.x;
    atomicAdd(&cnt[ldi(dst, j, i64)], 1);
}
__global__ void scan1_k(const int* __restrict__ cnt, int* __restrict__ row_start,
                        int* __restrict__ bsum){
    __shared__ int s[256];
    int t = threadIdx.x;
    int i = blockIdx.x*256 + t;
    int v = cnt[i];
    s[t] = v; __syncthreads();
    #pragma unroll
    for (int off=1; off<256; off<<=1){
        int add = (t>=off) ? s[t-off] : 0;
        __syncthreads();
        s[t] += add;
        __syncthreads();
    }
    row_start[i] = s[t] - v;
    if (t==255) bsum[blockIdx.x] = s[255];
}
__global__ void scan2_k(const int* __restrict__ bsum, int* __restrict__ boff){
    __shared__ int s[256];
    int t = threadIdx.x;
    int v = (t < NBLK) ? bsum[t] : 0;
    s[t] = v; __syncthreads();
    #pragma unroll
    for (int off=1; off<256; off<<=1){
        int add = (t>=off) ? s[t-off] : 0;
        __syncthreads();
        s[t] += add;
        __syncthreads();
    }
    if (t < NBLK) boff[t] = s[t] - v;
}
__global__ void scan3_k(int* __restrict__ row_start, const int* __restrict__ boff,
                        int* __restrict__ cursor){
    int i = blockIdx.x*256 + threadIdx.x;
    int x = row_start[i] + boff[blockIdx.x];
    row_start[i] = x;
    cursor[i] = x;
}
__global__ void scatter_k(const int* __restrict__ dst, int* __restrict__ cursor,
                          int* __restrict__ perm, const int* __restrict__ flags){
    int i64 = flags[1];
    int j = blockIdx.x*256 + threadIdx.x;
    int d = ldi(dst, j, i64);
    int p = atomicAdd(&cursor[d], 1);
    perm[p] = j;
}

// ---------------- e init (f16, CSR order, VECTORIZED) + meta build ----------
// One thread per 4 channels: 8-byte stores (4x fewer memory ops than R16's
// 2-byte). Same per-channel math/order -> bit-identical output.
// meta[p] = src16 | ((dst&7) << 16), written into perm's own storage.
__global__ void einit_k(const void* __restrict__ ef, const float* __restrict__ Wee,
                        const float* __restrict__ bee, const int* perm,
                        int* meta, const int* __restrict__ src,
                        const int* __restrict__ dst,
                        _Float16* __restrict__ e, const int* __restrict__ flags){
    int f = flags[0], i64 = flags[1];
    int tid = blockIdx.x*256 + threadIdx.x;     // NE*16 threads
    int q = tid & 15, p = tid >> 4;
    int c0 = q*4;
    int j = perm[p];
    float f0 = ldf3(ef, (size_t)j*2+0, f), f1 = ldf3(ef, (size_t)j*2+1, f);
    _Float16 v0 = (_Float16)(bee[c0+0] + f0*Wee[c0+0] + f1*Wee[64+c0+0]);
    _Float16 v1 = (_Float16)(bee[c0+1] + f0*Wee[c0+1] + f1*Wee[64+c0+1]);
    _Float16 v2 = (_Float16)(bee[c0+2] + f0*Wee[c0+2] + f1*Wee[64+c0+2]);
    _Float16 v3 = (_Float16)(bee[c0+3] + f0*Wee[c0+3] + f1*Wee[64+c0+3]);
    unsigned short u0, u1, u2, u3;
    __builtin_memcpy(&u0, &v0, 2); __builtin_memcpy(&u1, &v1, 2);
    __builtin_memcpy(&u2, &v2, 2); __builtin_memcpy(&u3, &v3, 2);
    uint2 pk;
    pk.x = (unsigned)u0 | ((unsigned)u1 << 16);
    pk.y = (unsigned)u2 | ((unsigned)u3 << 16);
    *(uint2*)&e[(size_t)p*64 + c0] = pk;
    if (q == 0)
        meta[p] = (ldi(src, j, i64) & 0xffff) | ((ldi(dst, j, i64) & 7) << 16);
    if (p < 16 && q == 1) meta[NE + p] = 0;
}

// ---------------- per-layer node transforms: 4 nodes per WAVE --------------
// EBi[i*64+c] = pack(f16 Eh, f16 Bh)  (one dword gather per edge in gg_k)
// AD16[i][0:64)=Ah, [64:128)=Dh+bC.
__global__ __launch_bounds__(256) void node4_k(int l, const float* __restrict__ h,
        const float* __restrict__ Wlc, const float* __restrict__ blc,
        unsigned* __restrict__ EBi, _Float16* __restrict__ AD){
    int t = threadIdx.x, c = t & 63, w = t >> 6;
    int i0 = blockIdx.x*16 + w*4;
    const float* WA = Wlc + (size_t)l*5*4096;
    const float* WB = WA + 4096;
    const float* WD = WA + 2*4096;
    const float* WE = WA + 3*4096;
    const float* bm = blc + (size_t)l*320;
    float hv0 = h[(size_t)(i0+0)*64 + c];
    float hv1 = h[(size_t)(i0+1)*64 + c];
    float hv2 = h[(size_t)(i0+2)*64 + c];
    float hv3 = h[(size_t)(i0+3)*64 + c];
    float ba = bm[c], bb = bm[64+c], bd = bm[128+c], be = bm[192+c];
    float ao0=ba, ao1=ba, ao2=ba, ao3=ba;
    float bo0=bb, bo1=bb, bo2=bb, bo3=bb;
    float do0=bd, do1=bd, do2=bd, do3=bd;
    float eo0=be, eo1=be, eo2=be, eo3=be;
    #pragma unroll 8
    for (int k=0;k<64;k++){
        float wa = WA[k*64+c], wb = WB[k*64+c], wd = WD[k*64+c], we = WE[k*64+c];
        float h0 = rl(hv0,k), h1 = rl(hv1,k), h2 = rl(hv2,k), h3 = rl(hv3,k);
        ao0 = fmaf(h0, wa, ao0); ao1 = fmaf(h1, wa, ao1);
        ao2 = fmaf(h2, wa, ao2); ao3 = fmaf(h3, wa, ao3);
        bo0 = fmaf(h0, wb, bo0); bo1 = fmaf(h1, wb, bo1);
        bo2 = fmaf(h2, wb, bo2); bo3 = fmaf(h3, wb, bo3);
        do0 = fmaf(h0, wd, do0); do1 = fmaf(h1, wd, do1);
        do2 = fmaf(h2, wd, do2); do3 = fmaf(h3, wd, do3);
        eo0 = fmaf(h0, we, eo0); eo1 = fmaf(h1, we, eo1);
        eo2 = fmaf(h2, we, eo2); eo3 = fmaf(h3, we, eo3);
    }
    float bc = bm[256+c];
    EBi[(size_t)(i0+0)*64 + c] = packh2(eo0, bo0);
    EBi[(size_t)(i0+1)*64 + c] = packh2(eo1, bo1);
    EBi[(size_t)(i0+2)*64 + c] = packh2(eo2, bo2);
    EBi[(size_t)(i0+3)*64 + c] = packh2(eo3, bo3);
    AD[(size_t)(i0+0)*128 + c] = (_Float16)ao0;
    AD[(size_t)(i0+0)*128 + 64 + c] = (_Float16)(do0 + bc);
    AD[(size_t)(i0+1)*128 + c] = (_Float16)ao1;
    AD[(size_t)(i0+1)*128 + 64 + c] = (_Float16)(do1 + bc);
    AD[(size_t)(i0+2)*128 + c] = (_Float16)ao2;
    AD[(size_t)(i0+2)*128 + 64 + c] = (_Float16)(do2 + bc);
    AD[(size_t)(i0+3)*128 + c] = (_Float16)ao3;
    AD[(size_t)(i0+3)*128 + 64 + c] = (_Float16)(do3 + bc);
}

// ---------------- fused MFMA-GEMM-gate-REGISTER-reduce: 8 nodes per block ---
// CHAMPION (R16, 2748->944 total): each wave owns TWO CONTIGUOUS nodes
// (local 2w, 2w+1 -> contiguous CSR range), accumulating num/den in 4
// REGISTERS selected by (dst&7)&1. No LDS atomics, no closing barrier.
// One dword gather EBi[src] yields (Eh,Bh). Unchanged this round.
__global__ __launch_bounds__(256) void gg_k(int l,
        _Float16* __restrict__ e, float* __restrict__ h,
        const unsigned* __restrict__ EBi, const _Float16* __restrict__ AD,
        const int* __restrict__ meta,
        const int* __restrict__ row_start,
        const unsigned short* __restrict__ WBf){
    __shared__ short WAs[4096];            // 8 KB  WC B-fragments (f16)
    __shared__ float T[4][16*68];          // 17.4 KB out-transpose

    int t = threadIdx.x, c = t & 63, w = t >> 6;
    int r16 = c & 15, kb = c >> 4;
    int i0 = blockIdx.x * 8;

    { // stage B-fragments (2048 u32, coalesced) into LDS
        const unsigned* wsrc = (const unsigned*)(WBf + (l << 12));
        unsigned* wdst = (unsigned*)WAs;
        for (int idx=t; idx<2048; idx+=256) wdst[idx] = wsrc[idx];
    }

    int n0 = i0 + 2*w;                     // wave owns nodes n0, n0+1
    float ah0 = (float)AD[(size_t)n0*128 + c];
    float ah1 = (float)AD[(size_t)(n0+1)*128 + c];
    float dh0 = (float)AD[(size_t)n0*128 + 64 + c];
    float dh1 = (float)AD[(size_t)(n0+1)*128 + 64 + c];
    int rsA = row_start[n0], rsC = row_start[n0+2];
    __syncthreads();                       // WAs ready

    float nm0 = 0.f, dn0 = 0.f, nm1 = 0.f, dn1 = 0.f;
    float* Tw = T[w];
    const hfrag* BF = ((const hfrag*)WAs) + c;   // frag f at BF[f*64]

    for (int pt = rsA; pt < rsC; pt += 16){
        int nv = rsC - pt; if (nv > 16) nv = 16;
        const int* mp = meta + __builtin_amdgcn_readfirstlane(pt);

        // A-fragment rows straight from global as f16 (validated mapping)
        const _Float16* ea = e + (size_t)(pt + r16)*64 + kb*8;
        hfrag a0v = *(const hfrag*)(ea);
        hfrag a1v = *(const hfrag*)(ea + 32);

        facc ac0 = {0.f,0.f,0.f,0.f}, ac1 = {0.f,0.f,0.f,0.f};
        facc ac2 = {0.f,0.f,0.f,0.f}, ac3 = {0.f,0.f,0.f,0.f};
        {
            hfrag Bx = BF[0*64], By = BF[2*64];
            ac0 = __builtin_amdgcn_mfma_f32_16x16x32_f16(a0v, Bx, ac0, 0, 0, 0);
            Bx = BF[4*64];
            ac1 = __builtin_amdgcn_mfma_f32_16x16x32_f16(a0v, By, ac1, 0, 0, 0);
            By = BF[6*64];
            ac2 = __builtin_amdgcn_mfma_f32_16x16x32_f16(a0v, Bx, ac2, 0, 0, 0);
            Bx = BF[1*64];
            ac3 = __builtin_amdgcn_mfma_f32_16x16x32_f16(a0v, By, ac3, 0, 0, 0);
            By = BF[3*64];
            ac0 = __builtin_amdgcn_mfma_f32_16x16x32_f16(a1v, Bx, ac0, 0, 0, 0);
            Bx = BF[5*64];
            ac1 = __builtin_amdgcn_mfma_f32_16x16x32_f16(a1v, By, ac1, 0, 0, 0);
            By = BF[7*64];
            ac2 = __builtin_amdgcn_mfma_f32_16x16x32_f16(a1v, Bx, ac2, 0, 0, 0);
            ac3 = __builtin_amdgcn_mfma_f32_16x16x32_f16(a1v, By, ac3, 0, 0, 0);
        }

        // acc -> T (C/D layout: row=(kb*4+r), col=ct*16+r16), stride 68
        #define TA(ct) Tw[(kb*4+0)*68 + ct*16 + r16] = ac##ct[0]; \
                       Tw[(kb*4+1)*68 + ct*16 + r16] = ac##ct[1]; \
                       Tw[(kb*4+2)*68 + ct*16 + r16] = ac##ct[2]; \
                       Tw[(kb*4+3)*68 + ct*16 + r16] = ac##ct[3];
        TA(0) TA(1) TA(2) TA(3)
        #undef TA

        const _Float16* ep = e + (size_t)pt*64 + c;

        // meta + single-dword gathers + gate with register reduce
        #define LM(q) unsigned m##q = (unsigned)mp[q];
        #define LG(q) unsigned g##q = EBi[(size_t)(m##q & 0xffffu)*64 + c];
        #define GT(q) if (q < nv){ \
            int hi = (int)((m##q >> 16) & 1u); \
            float ehat = Tw[q*68 + c] + (hi ? dh1 : dh0) \
                       + us2f_f16((unsigned short)(g##q & 0xffffu)); \
            float sig = 1.0f/(1.0f + __expf(-ehat)); \
            float nb = sig * us2f_f16((unsigned short)(g##q >> 16)); \
            nm0 += hi ? 0.0f : nb;  nm1 += hi ? nb : 0.0f; \
            dn0 += hi ? 0.0f : sig; dn1 += hi ? sig : 0.0f; \
            e[(size_t)(pt+q)*64+c] = (_Float16)((float)ep[q*64] + fmaxf(ehat, 0.0f)); }

        // batch0
        E8(LM)
        E8(LG)
        E8(GT)
        // batch1
        E8B(LM)
        E8B(LG)
        E8B(GT)

        #undef LM
        #undef LG
        #undef GT
    }

    // per-wave h update for its 2 nodes (no barrier needed)
    {
        float hv = h[(size_t)n0*64 + c];
        h[(size_t)n0*64 + c] = hv + fmaxf(ah0 + nm0/(dn0 + 1e-6f), 0.0f);
    }
    {
        float hv = h[(size_t)(n0+1)*64 + c];
        h[(size_t)(n0+1)*64 + c] = hv + fmaxf(ah1 + nm1/(dn1 + 1e-6f), 0.0f);
    }
}

// ---------------- MLP head: wave per node (validated) ----------------
__global__ __launch_bounds__(256) void head_k(const float* __restrict__ h,
        const float* __restrict__ W1, const float* __restrict__ b1,
        const float* __restrict__ W2, const float* __restrict__ b2,
        float* __restrict__ out){
    int t = threadIdx.x, c = t & 63;
    int i = blockIdx.x*4 + (t >> 6);
    float hv = h[(size_t)i*64 + c];
    float z0 = b1[c], z1 = b1[64+c];
    #pragma unroll 8
    for (int k=0;k<64;k++){
        float hk = __shfl(hv, k);
        z0 += hk * W1[k*128+c];
        z1 += hk * W1[k*128+64+c];
    }
    z0 = fmaxf(z0, 0.0f); z1 = fmaxf(z1, 0.0f);
    float o0 = z0*W2[c*2+0] + z1*W2[(64+c)*2+0];
    float o1 = z0*W2[c*2+1] + z1*W2[(64+c)*2+1];
    #pragma unroll
    for (int off=32; off; off>>=1){
        o0 += __shfl_xor(o0, off);
        o1 += __shfl_xor(o1, off);
    }
    if (c == 0){
        out[(size_t)i*2+0] = -1.2f*tanhf(o0 + b2[0]);
        out[(size_t)i*2+1] = -1.2f*tanhf(o1 + b2[1]);
    }
}

extern "C" void kernel_launch(void* const* d_in, const int* in_sizes, int n_in,
                              void* d_out, int out_size, void* d_ws, size_t ws_size,
                              hipStream_t stream){
    float* out = (float*)d_out;
    int fill_blocks = (out_size + 255) / 256;

    if (n_in != 14){
        fill_k<<<fill_blocks, 256, 0, stream>>>(out, out_size, 0.25f);
        return;
    }
    const int exp_sizes[14] = {300000, 1600000, 800000, 800000, 384, 64, 128, 64,
                               81920, 1280, 8192, 128, 256, 2};
    bool sizes_ok = (out_size == 100000);
    for (int i=0;i<14;i++) if (in_sizes[i] != exp_sizes[i]) sizes_ok = false;
    if (!sizes_ok){
        fill_k<<<fill_blocks, 256, 0, stream>>>(out, out_size, 0.5f);
        return;
    }

    // ---- ws layout, ~146 MB (well under known-good) ----
    size_t need = 0;
    size_t o_flags = need; need += 16;
    size_t o_rs   = need; need += (size_t)NP*4;
    size_t o_cur  = need; need += (size_t)NP*4;
    size_t o_bsum = need; need += (size_t)NBLK*4;
    size_t o_boff = need; need += (size_t)NBLK*4;
    size_t o_Weh  = need; need += 384ull*4;
    size_t o_beh  = need; need += 64ull*4;
    size_t o_Wee  = need; need += 128ull*4;
    size_t o_bee  = need; need += 64ull*4;
    size_t o_Wl   = need; need += 81920ull*4;
    size_t o_bl   = need; need += 1280ull*4;
    size_t o_W1   = need; need += 8192ull*4;
    size_t o_b1   = need; need += 128ull*4;
    size_t o_W2   = need; need += 256ull*4;
    size_t o_b2   = need; need += 2ull*4;
    size_t o_WBf  = need; need += 16384ull*2;   // MFMA B-fragments, 4 layers
    need = (need + 255) & ~(size_t)255;
    size_t o_perm = need; need += (size_t)(NE+16)*4;   // perm, reused as meta
    need = (need + 255) & ~(size_t)255;
    size_t o_h    = need; need += (size_t)NN*64*4;
    size_t o_EB   = need; need += (size_t)NN*64*4;     // EBi u32 (Eh|Bh f16)
    size_t o_AD   = need; need += (size_t)NN*128*2;    // f16
    need = (need + 255) & ~(size_t)255;
    size_t o_e    = need; need += (size_t)(NE+16)*64*2;  // f16 e, +16 rows pad
    if (ws_size < need){
        fill_k<<<fill_blocks, 256, 0, stream>>>(out, out_size, 0.75f);
        return;
    }

    char* p = (char*)d_ws;
    int*   flags = (int*)(p + o_flags);
    int*   row_start = (int*)(p + o_rs);
    int*   cursor    = (int*)(p + o_cur);
    int*   bsum = (int*)(p + o_bsum);
    int*   boff = (int*)(p + o_boff);
    float* Weh = (float*)(p + o_Weh);
    float* beh = (float*)(p + o_beh);
    float* Wee = (float*)(p + o_Wee);
    float* bee = (float*)(p + o_bee);
    float* Wlc = (float*)(p + o_Wl);
    float* blc = (float*)(p + o_bl);
    float* W1c = (float*)(p + o_W1);
    float* b1c = (float*)(p + o_b1);
    float* W2c = (float*)(p + o_W2);
    float* b2c = (float*)(p + o_b2);
    unsigned short* WBf = (unsigned short*)(p + o_WBf);
    int*   perm = (int*)(p + o_perm);       // reused as meta after einit
    float* h  = (float*)(p + o_h);
    unsigned* EBi = (unsigned*)(p + o_EB);
    _Float16* AD = (_Float16*)(p + o_AD);
    _Float16* e  = (_Float16*)(p + o_e);
    int* cnt = cursor;

    const int* src = (const int*)d_in[2];
    const int* dst = (const int*)d_in[3];

    probe_f_k<<<1, 256, 0, stream>>>((const unsigned short*)d_in[0], flags);
    probe_i_k<<<1, 256, 0, stream>>>(dst, flags);

    // merged weight conversion: dst region [o_Weh .. o_b2) is contiguous
    cvtall_k<<<(92418+255)/256, 256, 0, stream>>>(d_in[4], d_in[5], d_in[6],
        d_in[7], d_in[8], d_in[9], d_in[10], d_in[11], d_in[12], d_in[13],
        Weh, flags);

    packb_k<<<64, 256, 0, stream>>>(Wlc, WBf);

    embed_k<<<NN/4, 256, 0, stream>>>(d_in[0], Weh, beh, h, flags);

    zero_cnt_k<<<NBLK, 256, 0, stream>>>(cnt);
    hist_k<<<NE/256, 256, 0, stream>>>(dst, cnt, flags);
    scan1_k<<<NBLK, 256, 0, stream>>>(cnt, row_start, bsum);
    scan2_k<<<1, 256, 0, stream>>>(bsum, boff);
    scan3_k<<<NBLK, 256, 0, stream>>>(row_start, boff, cursor);
    scatter_k<<<NE/256, 256, 0, stream>>>(dst, cursor, perm, flags);

    // einit (vectorized: 4 ch/thread) also builds meta[] in-place over perm[]
    einit_k<<<NE*16/256, 256, 0, stream>>>(d_in[1], Wee, bee, perm, perm, src, dst,
                                           e, flags);

    for (int l=0; l<4; l++){
        node4_k<<<NN/16, 256, 0, stream>>>(l, h, Wlc, blc, EBi, AD);
        gg_k<<<NN/8, 256, 0, stream>>>(l, e, h, EBi, AD, perm, row_start, WBf);
    }
    head_k<<<NN/4, 256, 0, stream>>>(h, W1c, b1c, W2c, b2c, out);
}